// Round 4
// baseline (111.272 us; speedup 1.0000x reference)
//
#include <hip/hip_runtime.h>
#include <hip/hip_bf16.h>

// Problem: B=2, L=64, F=128. Output (B, L(a), L(t), L(s), 2F) f32 = 512 MiB.
// out[b,a,t,s,0:128]   = mask * (P[b,s]-P[b,a])/(s-a)   [sign cancels -> no min/max]
// out[b,a,t,s,128:256] = mask * (P[b,s]-P[b,t])/(s-t)
// mask = (a!=t)&(a!=s)&(t!=s).  Pure write-BW bound: 512 MiB out, 64 KiB in.

#define B_ 2
#define L_ 64
#define F_ 128

typedef float f32x4 __attribute__((ext_vector_type(4)));

__device__ float g_P[B_ * (L_ + 1) * F_];   // prefix sums, 66.5 KB

__global__ void prefix_kernel(const float* __restrict__ x) {
    const int b = blockIdx.x;       // 0..1
    const int f = threadIdx.x;      // 0..127
    const float* xb = x + b * L_ * F_ + f;
    float* Pb = g_P + b * (L_ + 1) * F_ + f;

    float v[L_];
#pragma unroll
    for (int r = 0; r < L_; ++r) v[r] = xb[r * F_];

    float run = 0.0f;
    Pb[0] = 0.0f;
#pragma unroll
    for (int r = 0; r < L_; ++r) {
        run += v[r];
        Pb[(r + 1) * F_] = run;
    }
}

// One block per (b,a,t); 4 waves; wave w owns s in [16w, 16w+16) = 16 KiB
// contiguous. All P rows this wave needs are PRELOADED into registers
// (16 x f32x4 + 1), so the store loop has zero memory reads -> store issue
// is never blocked on load latency (structurally identical to fillBuffer).
__global__ __launch_bounds__(256) void writer_kernel(f32x4* __restrict__ out) {
    const int bat = blockIdx.x;          // (b*64 + a)*64 + t
    const int t = bat & 63;
    const int a = (bat >> 6) & 63;
    const int b = bat >> 12;
    const int tid = threadIdx.x;
    const int f4 = tid & 63;             // float4 index within the 256-float row
    const int sw = tid >> 6;             // wave id 0..3
    const int s0 = sw << 4;              // this wave's first s
    f32x4* o = out + (size_t)bat * 4096 + s0 * 64 + f4;

    const f32x4 z = {0.f, 0.f, 0.f, 0.f};

    if (a == t) {                        // whole (a,t) plane is masked out
#pragma unroll
        for (int k = 0; k < 16; ++k)
            __builtin_nontemporal_store(z, o + k * 64);
        return;
    }

    // lanes 0..31 -> first half (i = a); lanes 32..63 -> second half (i = t)
    const int i = (f4 < 32) ? a : t;
    const float* base = g_P + ((b * (L_ + 1)) << 7) + ((f4 & 31) << 2);

    // Preload every P row this wave will touch (independent loads, all in
    // flight at once; L1/L2-resident).
    f32x4 p[16];
#pragma unroll
    for (int k = 0; k < 16; ++k)
        p[k] = *reinterpret_cast<const f32x4*>(base + ((s0 + k) << 7));
    const f32x4 pi = *reinterpret_cast<const f32x4*>(base + (i << 7));
    const float fi = (float)i;

#pragma unroll
    for (int k = 0; k < 16; ++k) {
        const int s = s0 + k;            // wave-uniform
        f32x4 v;
        if (s == a || s == t) {          // wave-uniform branch; else-path has s!=i
            v = z;
        } else {
            const float r = __builtin_amdgcn_rcpf((float)s - fi);
            v = (p[k] - pi) * r;         // (P[s]-P[i])/(s-i): sign cancels
        }
        __builtin_nontemporal_store(v, o + k * 64);
    }
}

extern "C" void kernel_launch(void* const* d_in, const int* in_sizes, int n_in,
                              void* d_out, int out_size, void* d_ws, size_t ws_size,
                              hipStream_t stream) {
    const float* x = (const float*)d_in[0];
    f32x4* out = (f32x4*)d_out;

    prefix_kernel<<<B_, F_, 0, stream>>>(x);
    writer_kernel<<<B_ * L_ * L_, 256, 0, stream>>>(out);
}

// Round 5
// 105.425 us; speedup vs baseline: 1.0555x; 1.0555x over previous
//
#include <hip/hip_runtime.h>
#include <hip/hip_bf16.h>

// Problem: B=2, L=64, F=128. Output (B, L(a), L(t), L(s), 2F) f32 = 512 MiB.
// out[b,a,t,s,0:128]   = mask * (P[b,s]-P[b,a])/(s-a)   [sign cancels -> no min/max]
// out[b,a,t,s,128:256] = mask * (P[b,s]-P[b,t])/(s-t)
// mask = (a!=t)&(a!=s)&(t!=s).  Pure write-BW bound: 512 MiB out, 64 KiB in.
//
// R5 A/B: identical to R4 except plain stores instead of nontemporal.
// (fillBufferAligned hits 6.6-6.9 TB/s on this chip WITHOUT nt; we sit at
// ~5.2 TB/s WITH nt across three structural variants.)

#define B_ 2
#define L_ 64
#define F_ 128

typedef float f32x4 __attribute__((ext_vector_type(4)));

__device__ float g_P[B_ * (L_ + 1) * F_];   // prefix sums, 66.5 KB

__global__ void prefix_kernel(const float* __restrict__ x) {
    const int b = blockIdx.x;       // 0..1
    const int f = threadIdx.x;      // 0..127
    const float* xb = x + b * L_ * F_ + f;
    float* Pb = g_P + b * (L_ + 1) * F_ + f;

    float v[L_];
#pragma unroll
    for (int r = 0; r < L_; ++r) v[r] = xb[r * F_];

    float run = 0.0f;
    Pb[0] = 0.0f;
#pragma unroll
    for (int r = 0; r < L_; ++r) {
        run += v[r];
        Pb[(r + 1) * F_] = run;
    }
}

// One block per (b,a,t); 4 waves; wave w owns s in [16w, 16w+16) = 16 KiB
// contiguous. P rows preloaded to registers; store loop is load-free.
__global__ __launch_bounds__(256) void writer_kernel(f32x4* __restrict__ out) {
    const int bat = blockIdx.x;          // (b*64 + a)*64 + t
    const int t = bat & 63;
    const int a = (bat >> 6) & 63;
    const int b = bat >> 12;
    const int tid = threadIdx.x;
    const int f4 = tid & 63;             // float4 index within the 256-float row
    const int sw = tid >> 6;             // wave id 0..3
    const int s0 = sw << 4;              // this wave's first s
    f32x4* o = out + (size_t)bat * 4096 + s0 * 64 + f4;

    const f32x4 z = {0.f, 0.f, 0.f, 0.f};

    if (a == t) {                        // whole (a,t) plane is masked out
#pragma unroll
        for (int k = 0; k < 16; ++k)
            o[k * 64] = z;
        return;
    }

    // lanes 0..31 -> first half (i = a); lanes 32..63 -> second half (i = t)
    const int i = (f4 < 32) ? a : t;
    const float* base = g_P + ((b * (L_ + 1)) << 7) + ((f4 & 31) << 2);

    f32x4 p[16];
#pragma unroll
    for (int k = 0; k < 16; ++k)
        p[k] = *reinterpret_cast<const f32x4*>(base + ((s0 + k) << 7));
    const f32x4 pi = *reinterpret_cast<const f32x4*>(base + (i << 7));
    const float fi = (float)i;

#pragma unroll
    for (int k = 0; k < 16; ++k) {
        const int s = s0 + k;            // wave-uniform
        f32x4 v;
        if (s == a || s == t) {          // wave-uniform branch; else-path has s!=i
            v = z;
        } else {
            const float r = __builtin_amdgcn_rcpf((float)s - fi);
            v = (p[k] - pi) * r;         // (P[s]-P[i])/(s-i): sign cancels
        }
        o[k * 64] = v;
    }
}

extern "C" void kernel_launch(void* const* d_in, const int* in_sizes, int n_in,
                              void* d_out, int out_size, void* d_ws, size_t ws_size,
                              hipStream_t stream) {
    const float* x = (const float*)d_in[0];
    f32x4* out = (f32x4*)d_out;

    prefix_kernel<<<B_, F_, 0, stream>>>(x);
    writer_kernel<<<B_ * L_ * L_, 256, 0, stream>>>(out);
}

// Round 6
// 102.011 us; speedup vs baseline: 1.0908x; 1.0335x over previous
//
#include <hip/hip_runtime.h>
#include <hip/hip_bf16.h>

// Problem: B=2, L=64, F=128. Output (B, L(a), L(t), L(s), 2F) f32 = 512 MiB.
// out[b,a,t,s,0:128]   = mask * (P[b,s]-P[b,a])/(s-a)   [sign cancels]
// out[b,a,t,s,128:256] = mask * (P[b,s]-P[b,t])/(s-t)
// mask = (a!=t)&(a!=s)&(t!=s).  Pure write-BW bound: 512 MiB out, 64 KiB in.
//
// R6: block = (b, a, 4 consecutive t). p[16] preload shared across the 4
// t-planes -> L2 read traffic 557 MB -> 176 MB; per-block startup amortized 4x.
// Plain stores (R5: nt hurts).

#define B_ 2
#define L_ 64
#define F_ 128

typedef float f32x4 __attribute__((ext_vector_type(4)));

__device__ float g_P[B_ * (L_ + 1) * F_];   // prefix sums, 66.5 KB

__global__ void prefix_kernel(const float* __restrict__ x) {
    const int b = blockIdx.x;       // 0..1
    const int f = threadIdx.x;      // 0..127
    const float* xb = x + b * L_ * F_ + f;
    float* Pb = g_P + b * (L_ + 1) * F_ + f;

    float v[L_];
#pragma unroll
    for (int r = 0; r < L_; ++r) v[r] = xb[r * F_];

    float run = 0.0f;
    Pb[0] = 0.0f;
#pragma unroll
    for (int r = 0; r < L_; ++r) {
        run += v[r];
        Pb[(r + 1) * F_] = run;
    }
}

// One block per (b, a, t-group of 4): 2048 blocks, 256 KiB contiguous each.
// 4 waves; wave w owns s in [16w, 16w+16) for every t in the group.
__global__ __launch_bounds__(256) void writer_kernel(f32x4* __restrict__ out) {
    const int bid = blockIdx.x;          // (b*64 + a)*16 + tg
    const int tg = bid & 15;
    const int a  = (bid >> 4) & 63;
    const int b  = bid >> 10;
    const int t0 = tg << 2;
    const int tid = threadIdx.x;
    const int f4 = tid & 63;             // float4 index within the 256-float row
    const int s0 = (tid >> 6) << 4;      // this wave's first s

    // out index (f32x4 units): (((b*64+a)*64 + t)*64 + s)*64 + f4
    f32x4* o = out + ((size_t)(((b << 6) + a) << 6) + t0) * 4096 + s0 * 64 + f4;

    const f32x4 z = {0.f, 0.f, 0.f, 0.f};
    const bool lower = (f4 < 32);        // lanes 0..31: i=a half; 32..63: i=t half
    const float* base = g_P + ((b * (L_ + 1)) << 7) + ((f4 & 31) << 2);

    // Preload all P rows this block needs (shared across the 4 t-planes).
    f32x4 p[16];
#pragma unroll
    for (int k = 0; k < 16; ++k)
        p[k] = *reinterpret_cast<const f32x4*>(base + ((s0 + k) << 7));
    const f32x4 pa = *reinterpret_cast<const f32x4*>(base + (a << 7));
    f32x4 pt[4];
#pragma unroll
    for (int tt = 0; tt < 4; ++tt)
        pt[tt] = *reinterpret_cast<const f32x4*>(base + ((t0 + tt) << 7));
    const float fa = (float)a;

#pragma unroll
    for (int tt = 0; tt < 4; ++tt) {
        const int t = t0 + tt;
        const bool plane_zero = (a == t);            // block-uniform
        const f32x4 pi = lower ? pa : pt[tt];        // per-lane select
        const float fi = lower ? fa : (float)t;
        f32x4* ot = o + tt * 4096;

#pragma unroll
        for (int k = 0; k < 16; ++k) {
            const int s = s0 + k;                    // wave-uniform
            f32x4 v;
            if (plane_zero || s == a || s == t) {    // wave-uniform
                v = z;
            } else {                                  // here s != i for all lanes
                const float r = __builtin_amdgcn_rcpf((float)s - fi);
                v = (p[k] - pi) * r;
            }
            ot[k * 64] = v;
        }
    }
}

extern "C" void kernel_launch(void* const* d_in, const int* in_sizes, int n_in,
                              void* d_out, int out_size, void* d_ws, size_t ws_size,
                              hipStream_t stream) {
    const float* x = (const float*)d_in[0];
    f32x4* out = (f32x4*)d_out;

    prefix_kernel<<<B_, F_, 0, stream>>>(x);
    writer_kernel<<<B_ * L_ * (L_ / 4), 256, 0, stream>>>(out);
}